// Round 8
// baseline (482.646 us; speedup 1.0000x reference)
//
#include <hip/hip_runtime.h>
#include <math.h>

#define NXC 432
#define NYC 496
#define CELLS (NYC * NXC)          // 214272
#define BATCH 4
#define PTOT 48000
#define EPSC 1e-3f
#define TCELLS 128                 // emit tile (CELLS % 128 == 0)

// DIAGNOSTIC ROUND: in-kernel body repetition so each dispatch exceeds the
// ~127us harness fills and appears in rocprof top-5 with full counters.
// t_pfe = pfe_dispatch_dur / 10 ; t_emit = emit_dispatch_dur / 4.
#define PFE_REP 10
#define EMIT_REP 4

typedef float f4v    __attribute__((ext_vector_type(4)));
typedef float f32x16 __attribute__((ext_vector_type(16)));
typedef __bf16 bf16x8 __attribute__((ext_vector_type(8)));

// ---------------------------------------------------------------------------
// Kernel 1: per-pillar fused dual-PFN via MFMA (body identical to round 7).
// ---------------------------------------------------------------------------
__global__ __launch_bounds__(256) void pfe_kernel(
    const float* __restrict__ pillars, const float* __restrict__ w1,
    const float* __restrict__ bn1, const float* __restrict__ w2,
    const float* __restrict__ bn2, const float* __restrict__ wf1,
    const float* __restrict__ wf2, const float* __restrict__ fbn1,
    const float* __restrict__ fbn2, const int* __restrict__ coords,
    const int* __restrict__ num_points, float* __restrict__ comb,
    int* __restrict__ map)
{
    const int tid  = threadIdx.x;
    const int lane = tid & 63;
    const int ln   = lane & 31;               // point index / channel-in-tile
    const bool hi  = lane >= 32;
    const int p = __builtin_amdgcn_readfirstlane(blockIdx.x * 4 + (tid >> 6));
    const float* __restrict__ pl = pillars + (size_t)p * 256;

    for (int rep = 0; rep < PFE_REP; ++rep) {
        asm volatile("" ::: "memory");   // defeat LICM: re-run the whole body

        const f4v v0 = *(const f4v*)(pl + ln * 8);
        const f4v v1 = *(const f4v*)(pl + ln * 8 + 4);

        float sx = v0.x, sy = v0.y, sz = v0.z;
#pragma unroll
        for (int off = 1; off <= 16; off <<= 1) {
            sx += __shfl_xor(sx, off);
            sy += __shfl_xor(sy, off);
            sz += __shfl_xor(sz, off);
        }
        const float inv_np = 1.0f / (float)num_points[p];
        const float mxm = sx * inv_np, mym = sy * inv_np, mzm = sz * inv_np;

        const int c1 = coords[p * 4 + 1], c2 = coords[p * 4 + 2], c3 = coords[p * 4 + 3];
        const float cx = c3 * 0.16f + 0.08f;
        const float cy = c2 * 0.16f + (-39.6f);
        const float cz = c1 * 4.0f  + (-1.0f);

        float AXc[2], AYc[2], AZc[2], AIc[2], C0c[2];
        float Bc[2][8], C2c[2], WF1c[2], WF2c[2];
#pragma unroll
        for (int i = 0; i < 2; ++i) {
            const int c = ln + i * 32;
            const float s1 = bn1[c] * rsqrtf(bn1[192 + c] + EPSC);
            const float be1 = bn1[64 + c], bm1 = bn1[128 + c];
            const float w10 = w1[c],       w11 = w1[64 + c],  w12 = w1[128 + c];
            const float w13 = w1[192 + c], w14 = w1[256 + c], w15 = w1[320 + c];
            const float w16 = w1[384 + c], w17 = w1[448 + c], w18 = w1[512 + c];
            const float w19 = w1[576 + c];
            AXc[i] = (w10 + w14 + w17) * s1;
            AYc[i] = (w11 + w15 + w18) * s1;
            AZc[i] = (w12 + w16 + w19) * s1;
            AIc[i] = w13 * s1;
            C0c[i] = be1 - bm1 * s1
                   - (mxm * w14 + mym * w15 + mzm * w16) * s1
                   - (cx * w17 + cy * w18 + cz * w19) * s1;

            const float s2 = bn2[c] * rsqrtf(bn2[192 + c] + EPSC);
#pragma unroll
            for (int k = 0; k < 8; ++k) Bc[i][k] = w2[k * 64 + c] * s2;
            C2c[i] = bn2[64 + c] - bn2[128 + c] * s2;
            WF1c[i] = wf1[c];
            WF2c[i] = wf2[c];
        }

        bf16x8 a;
        {
            const float f[8] = {v0.x, v0.y, v0.z, v0.w, v1.x, v1.y, v1.z, v1.w};
#pragma unroll
            for (int e = 0; e < 8; ++e) {
                const __bf16 h = (__bf16)f[e];
                const __bf16 l = (__bf16)(f[e] - (float)h);
                a[e] = hi ? l : h;
            }
        }

        const bf16x8 b0 = {(__bf16)AXc[0], (__bf16)AYc[0], (__bf16)AZc[0], (__bf16)AIc[0],
                           (__bf16)0.f, (__bf16)0.f, (__bf16)0.f, (__bf16)0.f};
        const bf16x8 b1 = {(__bf16)AXc[1], (__bf16)AYc[1], (__bf16)AZc[1], (__bf16)AIc[1],
                           (__bf16)0.f, (__bf16)0.f, (__bf16)0.f, (__bf16)0.f};
        const bf16x8 b2 = {(__bf16)Bc[0][0], (__bf16)Bc[0][1], (__bf16)Bc[0][2], (__bf16)Bc[0][3],
                           (__bf16)Bc[0][4], (__bf16)Bc[0][5], (__bf16)Bc[0][6], (__bf16)Bc[0][7]};
        const bf16x8 b3 = {(__bf16)Bc[1][0], (__bf16)Bc[1][1], (__bf16)Bc[1][2], (__bf16)Bc[1][3],
                           (__bf16)Bc[1][4], (__bf16)Bc[1][5], (__bf16)Bc[1][6], (__bf16)Bc[1][7]};

        f32x16 d0 = {0.f}, d1 = {0.f}, d2 = {0.f}, d3 = {0.f};
        d0 = __builtin_amdgcn_mfma_f32_32x32x16_bf16(a, b0, d0, 0, 0, 0);
        d1 = __builtin_amdgcn_mfma_f32_32x32x16_bf16(a, b1, d1, 0, 0, 0);
        d2 = __builtin_amdgcn_mfma_f32_32x32x16_bf16(a, b2, d2, 0, 0, 0);
        d3 = __builtin_amdgcn_mfma_f32_32x32x16_bf16(a, b3, d3, 0, 0, 0);

        float m0 = d0[0], m1 = d1[0], m2 = d2[0], m3 = d3[0];
#pragma unroll
        for (int r = 1; r < 16; ++r) {
            m0 = fmaxf(m0, d0[r]); m1 = fmaxf(m1, d1[r]);
            m2 = fmaxf(m2, d2[r]); m3 = fmaxf(m3, d3[r]);
        }
        m0 = fmaxf(m0, __shfl_xor(m0, 32));
        m1 = fmaxf(m1, __shfl_xor(m1, 32));
        m2 = fmaxf(m2, __shfl_xor(m2, 32));
        m3 = fmaxf(m3, __shfl_xor(m3, 32));

        const float f1A = fmaxf(m0 + C0c[0], 0.f);
        const float f1B = fmaxf(m1 + C0c[1], 0.f);
        const float f2A = fmaxf(m2 + C2c[0], 0.f);
        const float f2B = fmaxf(m3 + C2c[1], 0.f);

        float dd1 = f1A * WF1c[0] + f1B * WF1c[1];
        float dd2 = f2A * WF2c[0] + f2B * WF2c[1];
#pragma unroll
        for (int off = 1; off <= 16; off <<= 1) {
            dd1 += __shfl_xor(dd1, off);
            dd2 += __shfl_xor(dd2, off);
        }
        const float sc1 = (dd1 - fbn1[2]) * (fbn1[0] * rsqrtf(fbn1[3] + EPSC)) + fbn1[1];
        const float sc2 = (dd2 - fbn2[2]) * (fbn2[0] * rsqrtf(fbn2[3] + EPSC)) + fbn2[1];
        const float a0 = 1.0f / (1.0f + expf(sc2 - sc1));

        if (!hi) {
            comb[p * 64 + ln]      = fmaf(f1A - f2A, a0, f2A);
            comb[p * 64 + 32 + ln] = fmaf(f1B - f2B, a0, f2B);
        }
        if (lane == 0) {
            const int lin = c1 + c2 * NXC + c3;
            map[coords[p * 4 + 0] * CELLS + lin] = p;
        }
    }
}

// ---------------------------------------------------------------------------
// Kernel 2: dense emit via LDS transpose (body identical to round 7).
// ---------------------------------------------------------------------------
__global__ __launch_bounds__(256) void emit_kernel(
    const int* __restrict__ map, const float* __restrict__ comb,
    float* __restrict__ out)
{
    __shared__ float lds[64 * 132];           // [ch][cell], pad 132 words
    const int t = threadIdx.x;
    const int gbase = blockIdx.x * TCELLS;

    for (int rep = 0; rep < EMIT_REP; ++rep) {
        asm volatile("" ::: "memory");   // defeat LICM

        {
            const int c = t >> 1;
            const int h = (t & 1) * 32;
            const int m = map[gbase + c];
            float* dst = lds + h * 132 + c;
            if (m >= 0) {
                const float* src = comb + (size_t)m * 64 + h;
#pragma unroll
                for (int j = 0; j < 8; j++) {
                    const float4 v = *(const float4*)(src + j * 4);
                    dst[(j * 4 + 0) * 132] = v.x;
                    dst[(j * 4 + 1) * 132] = v.y;
                    dst[(j * 4 + 2) * 132] = v.z;
                    dst[(j * 4 + 3) * 132] = v.w;
                }
            } else {
#pragma unroll
                for (int j = 0; j < 32; j++) dst[j * 132] = 0.f;
            }
        }
        __syncthreads();

        const int b = gbase / CELLS;
        const int L = gbase - b * CELLS;
        float* obase = out + (size_t)(b * 64) * CELLS + L;
#pragma unroll
        for (int r = 0; r < 8; r++) {
            const int idx = r * 256 + t;
            const int f = idx >> 5;
            const int g = idx & 31;
            const f4v v = *(const f4v*)(lds + f * 132 + g * 4);
            __builtin_nontemporal_store(v, (f4v*)(obase + (size_t)f * CELLS + g * 4));
        }
        __syncthreads();                 // rep isolation
    }
}

extern "C" void kernel_launch(void* const* d_in, const int* in_sizes, int n_in,
                              void* d_out, int out_size, void* d_ws, size_t ws_size,
                              hipStream_t stream) {
    const float* pillars = (const float*)d_in[0];
    const float* w1      = (const float*)d_in[1];
    const float* bn1     = (const float*)d_in[2];
    const float* w2      = (const float*)d_in[3];
    const float* bn2     = (const float*)d_in[4];
    const float* wf1     = (const float*)d_in[5];
    const float* wf2     = (const float*)d_in[6];
    const float* fbn1    = (const float*)d_in[7];
    const float* fbn2    = (const float*)d_in[8];
    const int*   coords  = (const int*)d_in[9];
    const int*   nump    = (const int*)d_in[10];
    float* out = (float*)d_out;

    int*   map  = (int*)d_ws;
    float* comb = (float*)((char*)d_ws + (size_t)BATCH * CELLS * 4);

    (void)hipMemsetAsync(map, 0xFF, (size_t)BATCH * CELLS * 4, stream);  // all -1
    pfe_kernel<<<PTOT / 4, 256, 0, stream>>>(pillars, w1, bn1, w2, bn2,
                                             wf1, wf2, fbn1, fbn2,
                                             coords, nump, comb, map);
    emit_kernel<<<(BATCH * CELLS) / TCELLS, 256, 0, stream>>>(map, comb, out);
}

// Round 9
// 83.882 us; speedup vs baseline: 5.7538x; 5.7538x over previous
//
#include <hip/hip_runtime.h>
#include <math.h>

#define NXC 432
#define NYC 496
#define CELLS (NYC * NXC)          // 214272
#define BATCH 4
#define PTOT 48000
#define EPSC 1e-3f
#define TCELLS 128                 // emit tile (CELLS % 128 == 0)
#define TBL_STRIDE 20              // words per channel in fold table

typedef float f2v    __attribute__((ext_vector_type(2)));
typedef float f4v    __attribute__((ext_vector_type(4)));
typedef float f32x16 __attribute__((ext_vector_type(16)));
typedef __bf16 bf16x8 __attribute__((ext_vector_type(8)));
typedef unsigned int u32x4 __attribute__((ext_vector_type(4)));

// ---------------------------------------------------------------------------
// Kernel 0: fold BN+weights into per-channel constants (pillar-independent).
// tbl[c*20 + 0..3]: branch1 B-fragment as packed bf16 pairs (AX,AY)(AZ,AI)(0)(0)
// tbl[c*20 + 4..7]: branch2 B-fragment packed bf16 (B0..B7)
// tbl[c*20 + 8..11]: K0_1, M1, M2, M3   (C0 = K0 - mean.M - center.P)
// tbl[c*20 +12..15]: P1, P2, P3, C2
// tbl[c*20 +16..17]: WF1, WF2
// ---------------------------------------------------------------------------
__device__ __forceinline__ unsigned int pk_bf16(float a, float b) {
    __bf16 ha = (__bf16)a, hb = (__bf16)b;
    unsigned short ua = __builtin_bit_cast(unsigned short, ha);
    unsigned short ub = __builtin_bit_cast(unsigned short, hb);
    return ((unsigned int)ub << 16) | ua;
}

__global__ __launch_bounds__(64) void fold_kernel(
    const float* __restrict__ w1, const float* __restrict__ bn1,
    const float* __restrict__ w2, const float* __restrict__ bn2,
    const float* __restrict__ wf1, const float* __restrict__ wf2,
    unsigned int* __restrict__ tbl)
{
    const int c = threadIdx.x;     // channel 0..63
    const float s1 = bn1[c] * rsqrtf(bn1[192 + c] + EPSC);
    const float w10 = w1[c],       w11 = w1[64 + c],  w12 = w1[128 + c];
    const float w13 = w1[192 + c], w14 = w1[256 + c], w15 = w1[320 + c];
    const float w16 = w1[384 + c], w17 = w1[448 + c], w18 = w1[512 + c];
    const float w19 = w1[576 + c];
    const float AX = (w10 + w14 + w17) * s1;
    const float AY = (w11 + w15 + w18) * s1;
    const float AZ = (w12 + w16 + w19) * s1;
    const float AI = w13 * s1;

    const float s2 = bn2[c] * rsqrtf(bn2[192 + c] + EPSC);
    float B[8];
#pragma unroll
    for (int k = 0; k < 8; ++k) B[k] = w2[k * 64 + c] * s2;

    unsigned int* t = tbl + c * TBL_STRIDE;
    t[0] = pk_bf16(AX, AY);
    t[1] = pk_bf16(AZ, AI);
    t[2] = 0u;
    t[3] = 0u;
    t[4] = pk_bf16(B[0], B[1]);
    t[5] = pk_bf16(B[2], B[3]);
    t[6] = pk_bf16(B[4], B[5]);
    t[7] = pk_bf16(B[6], B[7]);
    float* tf = (float*)t;
    tf[8]  = bn1[64 + c] - bn1[128 + c] * s1;   // K0_1
    tf[9]  = w14 * s1;                          // M1
    tf[10] = w15 * s1;                          // M2
    tf[11] = w16 * s1;                          // M3
    tf[12] = w17 * s1;                          // P1
    tf[13] = w18 * s1;                          // P2
    tf[14] = w19 * s1;                          // P3
    tf[15] = bn2[64 + c] - bn2[128 + c] * s2;   // C2
    tf[16] = wf1[c];
    tf[17] = wf2[c];
    tf[18] = 0.f; tf[19] = 0.f;
}

// ---------------------------------------------------------------------------
// Kernel 1: per-pillar fused dual-PFN via MFMA (fold table precomputed).
// One wave per pillar; bf16 hi/lo A-split (X exact, only W' rounded).
// Layouts (learn_hip m74/m101): D col=lane&31, row=(reg&3)+8*(reg>>2)+4*(lane>>5);
// A row=lane&31, k=(lane>>5)*8+e; B col=lane&31, k=(lane>>5)*8+e.
// ---------------------------------------------------------------------------
__global__ __launch_bounds__(256) void pfe_kernel(
    const float* __restrict__ pillars, const unsigned int* __restrict__ tbl,
    const float* __restrict__ fbn1, const float* __restrict__ fbn2,
    const int* __restrict__ coords, const int* __restrict__ num_points,
    float* __restrict__ comb, int* __restrict__ map)
{
    const int tid  = threadIdx.x;
    const int lane = tid & 63;
    const int ln   = lane & 31;
    const bool hi  = lane >= 32;
    const int p = __builtin_amdgcn_readfirstlane(blockIdx.x * 4 + (tid >> 6));
    const float* __restrict__ pl = pillars + (size_t)p * 256;

    // point ln's 8 features (hi half duplicates; coalesced)
    const f4v v0 = *(const f4v*)(pl + ln * 8);
    const f4v v1 = *(const f4v*)(pl + ln * 8 + 4);

    // mean xyz over all 32 points (reference does NOT mask)
    float sx = v0.x, sy = v0.y, sz = v0.z;
#pragma unroll
    for (int off = 1; off <= 16; off <<= 1) {
        sx += __shfl_xor(sx, off);
        sy += __shfl_xor(sy, off);
        sz += __shfl_xor(sz, off);
    }
    const float inv_np = 1.0f / (float)num_points[p];
    const float mxm = sx * inv_np, mym = sy * inv_np, mzm = sz * inv_np;

    const int c1 = coords[p * 4 + 1], c2 = coords[p * 4 + 2], c3 = coords[p * 4 + 3];
    const float cx = c3 * 0.16f + 0.08f;
    const float cy = c2 * 0.16f + (-39.6f);
    const float cz = c1 * 4.0f  + (-1.0f);

    // per-channel folded constants from table (L2-hot, 5 KB)
    bf16x8 bfr1[2], bfr2[2];
    float C0c[2], C2c[2], WF1c[2], WF2c[2];
#pragma unroll
    for (int i = 0; i < 2; ++i) {
        const unsigned int* t = tbl + (ln + i * 32) * TBL_STRIDE;
        bfr1[i] = __builtin_bit_cast(bf16x8, *(const u32x4*)t);
        bfr2[i] = __builtin_bit_cast(bf16x8, *(const u32x4*)(t + 4));
        const f4v k0 = *(const f4v*)(t + 8);    // K0, M1, M2, M3
        const f4v k1 = *(const f4v*)(t + 12);   // P1, P2, P3, C2
        const f2v wfp = *(const f2v*)(t + 16);  // WF1, WF2
        C0c[i] = k0.x - (mxm * k0.y + mym * k0.z + mzm * k0.w)
                      - (cx * k1.x + cy * k1.y + cz * k1.z);
        C2c[i] = k1.w;
        WF1c[i] = wfp.x;
        WF2c[i] = wfp.y;
    }

    // A fragment: lo lanes bf16-hi (k=0..7), hi lanes bf16-lo residual (k=8..15)
    bf16x8 a;
    {
        const float f[8] = {v0.x, v0.y, v0.z, v0.w, v1.x, v1.y, v1.z, v1.w};
#pragma unroll
        for (int e = 0; e < 8; ++e) {
            const __bf16 h = (__bf16)f[e];
            const __bf16 l = (__bf16)(f[e] - (float)h);
            a[e] = hi ? l : h;
        }
    }

    f32x16 d0 = {0.f}, d1 = {0.f}, d2 = {0.f}, d3 = {0.f};
    d0 = __builtin_amdgcn_mfma_f32_32x32x16_bf16(a, bfr1[0], d0, 0, 0, 0);
    d1 = __builtin_amdgcn_mfma_f32_32x32x16_bf16(a, bfr1[1], d1, 0, 0, 0);
    d2 = __builtin_amdgcn_mfma_f32_32x32x16_bf16(a, bfr2[0], d2, 0, 0, 0);
    d3 = __builtin_amdgcn_mfma_f32_32x32x16_bf16(a, bfr2[1], d3, 0, 0, 0);

    // max over points (rows): 15 in-lane max per tile + cross-half
    float m0 = d0[0], m1 = d1[0], m2 = d2[0], m3 = d3[0];
#pragma unroll
    for (int r = 1; r < 16; ++r) {
        m0 = fmaxf(m0, d0[r]); m1 = fmaxf(m1, d1[r]);
        m2 = fmaxf(m2, d2[r]); m3 = fmaxf(m3, d3[r]);
    }
    m0 = fmaxf(m0, __shfl_xor(m0, 32));
    m1 = fmaxf(m1, __shfl_xor(m1, 32));
    m2 = fmaxf(m2, __shfl_xor(m2, 32));
    m3 = fmaxf(m3, __shfl_xor(m3, 32));

    const float f1A = fmaxf(m0 + C0c[0], 0.f);
    const float f1B = fmaxf(m1 + C0c[1], 0.f);
    const float f2A = fmaxf(m2 + C2c[0], 0.f);
    const float f2B = fmaxf(m3 + C2c[1], 0.f);

    // attention scalars (each 32-half holds the full 64-channel set)
    float dd1 = f1A * WF1c[0] + f1B * WF1c[1];
    float dd2 = f2A * WF2c[0] + f2B * WF2c[1];
#pragma unroll
    for (int off = 1; off <= 16; off <<= 1) {
        dd1 += __shfl_xor(dd1, off);
        dd2 += __shfl_xor(dd2, off);
    }
    const float sc1 = (dd1 - fbn1[2]) * (fbn1[0] * rsqrtf(fbn1[3] + EPSC)) + fbn1[1];
    const float sc2 = (dd2 - fbn2[2]) * (fbn2[0] * rsqrtf(fbn2[3] + EPSC)) + fbn2[1];
    const float a0 = 1.0f / (1.0f + expf(sc2 - sc1));

    if (!hi) {
        comb[p * 64 + ln]      = fmaf(f1A - f2A, a0, f2A);
        comb[p * 64 + 32 + ln] = fmaf(f1B - f2B, a0, f2B);
    }
    if (lane == 0) {
        const int lin = c1 + c2 * NXC + c3;
        map[coords[p * 4 + 0] * CELLS + lin] = p;
    }
}

// ---------------------------------------------------------------------------
// Kernel 2: dense emit. Occupied cells (~6%) gather into LDS; empty 4-cell
// groups store zero-float4 directly (no LDS traffic at all).
// ---------------------------------------------------------------------------
__global__ __launch_bounds__(256) void emit_kernel(
    const int* __restrict__ map, const float* __restrict__ comb,
    float* __restrict__ out)
{
    __shared__ float lds[64 * 132];           // [ch][cell]; only occupied cols valid
    __shared__ int mcell[128];
    const int t = threadIdx.x;
    const int gbase = blockIdx.x * TCELLS;

    // phase 1: occupied-only gather -> LDS transposed; record map values
    {
        const int c = t >> 1;                 // cell within tile
        const int h = (t & 1) * 32;           // channel half
        const int m = map[gbase + c];
        if ((t & 1) == 0) mcell[c] = m;
        if (m >= 0) {
            const float* src = comb + (size_t)m * 64 + h;
            float* dst = lds + h * 132 + c;
#pragma unroll
            for (int j = 0; j < 8; j++) {
                const float4 v = *(const float4*)(src + j * 4);
                dst[(j * 4 + 0) * 132] = v.x;
                dst[(j * 4 + 1) * 132] = v.y;
                dst[(j * 4 + 2) * 132] = v.z;
                dst[(j * 4 + 3) * 132] = v.w;
            }
        }
    }
    __syncthreads();

    // phase 2: coalesced float4 nontemporal stores; zero fast path
    const int b = gbase / CELLS;
    const int L = gbase - b * CELLS;
    float* obase = out + (size_t)(b * 64) * CELLS + L;
#pragma unroll
    for (int r = 0; r < 8; r++) {
        const int idx = r * 256 + t;
        const int f = idx >> 5;               // channel
        const int g = idx & 31;               // float4 group along cells
        const int4 mg = *(const int4*)&mcell[g * 4];
        f4v v = {0.f, 0.f, 0.f, 0.f};
        if ((mg.x & mg.y & mg.z & mg.w) >= 0) {   // any cell occupied
            const f4v w = *(const f4v*)(lds + f * 132 + g * 4);
            v.x = (mg.x < 0) ? 0.f : w.x;
            v.y = (mg.y < 0) ? 0.f : w.y;
            v.z = (mg.z < 0) ? 0.f : w.z;
            v.w = (mg.w < 0) ? 0.f : w.w;
        }
        __builtin_nontemporal_store(v, (f4v*)(obase + (size_t)f * CELLS + g * 4));
    }
}

extern "C" void kernel_launch(void* const* d_in, const int* in_sizes, int n_in,
                              void* d_out, int out_size, void* d_ws, size_t ws_size,
                              hipStream_t stream) {
    const float* pillars = (const float*)d_in[0];
    const float* w1      = (const float*)d_in[1];
    const float* bn1     = (const float*)d_in[2];
    const float* w2      = (const float*)d_in[3];
    const float* bn2     = (const float*)d_in[4];
    const float* wf1     = (const float*)d_in[5];
    const float* wf2     = (const float*)d_in[6];
    const float* fbn1    = (const float*)d_in[7];
    const float* fbn2    = (const float*)d_in[8];
    const int*   coords  = (const int*)d_in[9];
    const int*   nump    = (const int*)d_in[10];
    float* out = (float*)d_out;

    int*   map  = (int*)d_ws;
    float* comb = (float*)((char*)d_ws + (size_t)BATCH * CELLS * 4);
    unsigned int* tbl = (unsigned int*)((char*)d_ws + (size_t)BATCH * CELLS * 4
                                        + (size_t)PTOT * 64 * 4);

    (void)hipMemsetAsync(map, 0xFF, (size_t)BATCH * CELLS * 4, stream);  // all -1
    fold_kernel<<<1, 64, 0, stream>>>(w1, bn1, w2, bn2, wf1, wf2, tbl);
    pfe_kernel<<<PTOT / 4, 256, 0, stream>>>(pillars, tbl, fbn1, fbn2,
                                             coords, nump, comb, map);
    emit_kernel<<<(BATCH * CELLS) / TCELLS, 256, 0, stream>>>(map, comb, out);
}